// Round 1
// baseline (307.519 us; speedup 1.0000x reference)
//
#include <hip/hip_runtime.h>

#define NH 16
#define HD 64
#define TSEQ 2048
#define DMODEL 1024

typedef __attribute__((ext_vector_type(8))) short short8;
typedef __attribute__((ext_vector_type(4))) float f32x4;

static __device__ __forceinline__ unsigned short f2bf(float f) {
    unsigned u = __builtin_bit_cast(unsigned, f);
    u += 0x7FFF + ((u >> 16) & 1);
    return (unsigned short)(u >> 16);
}

// ---------------- cast f32 -> bf16 (vectorized, n multiple of 4) ----------------
__global__ __launch_bounds__(256) void cast_f32_bf16(const float* __restrict__ src,
                                                     unsigned short* __restrict__ dst, int n4) {
    int i = blockIdx.x * 256 + threadIdx.x;
    if (i >= n4) return;
    float4 v = reinterpret_cast<const float4*>(src)[i];
    ushort4 o;
    o.x = f2bf(v.x); o.y = f2bf(v.y); o.z = f2bf(v.z); o.w = f2bf(v.w);
    reinterpret_cast<ushort4*>(dst)[i] = o;
}

// ---------------- m97-style GEMM mainloop: C[128x128] = A[M][K] * Bt[N][K]^T ----------------
// A, Bt bf16 row-major with row length K (=1024). Single-buffered LDS, global_load_lds width 16.
static __device__ __forceinline__ void gemm_mainloop(const unsigned short* __restrict__ A,
                                                     const unsigned short* __restrict__ Bt,
                                                     int m0, int n0, int K,
                                                     unsigned short* As, unsigned short* Bs,
                                                     f32x4 acc[4][4]) {
    const int tid = threadIdx.x;
    const int lane = tid & 63;
    const int w = tid >> 6;
    const int wr = w >> 1, wc = w & 1;
    const int lrow = lane >> 2;          // 0..15
    const int lcol = (lane & 3) * 8;     // 0,8,16,24  (ushort units)

    f32x4 zero = {0.f, 0.f, 0.f, 0.f};
#pragma unroll
    for (int i = 0; i < 4; i++)
#pragma unroll
        for (int j = 0; j < 4; j++) acc[i][j] = zero;

    for (int k0 = 0; k0 < K; k0 += 32) {
        __syncthreads();  // protect LDS from previous iteration's readers
#pragma unroll
        for (int c = w; c < 8; c += 4) {
            int row = c * 16 + lrow;
            __builtin_amdgcn_global_load_lds(
                (const __attribute__((address_space(1))) void*)(A + (size_t)(m0 + row) * K + k0 + lcol),
                (__attribute__((address_space(3))) void*)(As + c * 512), 16, 0, 0);
            __builtin_amdgcn_global_load_lds(
                (const __attribute__((address_space(1))) void*)(Bt + (size_t)(n0 + row) * K + k0 + lcol),
                (__attribute__((address_space(3))) void*)(Bs + c * 512), 16, 0, 0);
        }
        __syncthreads();  // compiler drains vmcnt before s_barrier

        const int ko = (lane >> 4) * 8;
        short8 a[4], b[4];
#pragma unroll
        for (int i = 0; i < 4; i++)
            a[i] = *(const short8*)(As + (wr * 64 + i * 16 + (lane & 15)) * 32 + ko);
#pragma unroll
        for (int j = 0; j < 4; j++)
            b[j] = *(const short8*)(Bs + (wc * 64 + j * 16 + (lane & 15)) * 32 + ko);
#pragma unroll
        for (int i = 0; i < 4; i++)
#pragma unroll
            for (int j = 0; j < 4; j++)
                acc[i][j] = __builtin_amdgcn_mfma_f32_16x16x32_bf16(a[i], b[j], acc[i][j], 0, 0, 0);
    }
}

// ---------------- QKV projection: z=0 -> Q[B,H,T,hd], z=1 -> K[B,H,T,hd], z=2 -> Vt[B,H,hd,T] ----------------
__global__ __launch_bounds__(256) void gemm_qkv(const unsigned short* __restrict__ xb,
                                                const unsigned short* __restrict__ Wqb,
                                                const unsigned short* __restrict__ Wkb,
                                                const unsigned short* __restrict__ Wvb,
                                                unsigned short* __restrict__ Q,
                                                unsigned short* __restrict__ K,
                                                unsigned short* __restrict__ Vt) {
    __shared__ __attribute__((aligned(16))) unsigned short As[128 * 32];
    __shared__ __attribute__((aligned(16))) unsigned short Bs[128 * 32];
    const int m0 = blockIdx.x * 128;
    const int n0 = blockIdx.y * 128;
    const int z = blockIdx.z;
    const unsigned short* Bt = (z == 0) ? Wqb : ((z == 1) ? Wkb : Wvb);
    unsigned short* out = (z == 0) ? Q : ((z == 1) ? K : Vt);

    f32x4 acc[4][4];
    gemm_mainloop(xb, Bt, m0, n0, DMODEL, As, Bs, acc);

    const int tid = threadIdx.x, lane = tid & 63, w = tid >> 6;
    const int wr = w >> 1, wc = w & 1;
#pragma unroll
    for (int i = 0; i < 4; i++)
#pragma unroll
        for (int j = 0; j < 4; j++)
#pragma unroll
            for (int r = 0; r < 4; r++) {
                int row = m0 + wr * 64 + i * 16 + (lane >> 4) * 4 + r;  // b*2048 + t
                int col = n0 + wc * 64 + j * 16 + (lane & 15);          // h*64 + d
                int b = row >> 11, t = row & 2047;
                int h = col >> 6, d = col & 63;
                unsigned short v = f2bf(acc[i][j][r]);
                if (z == 2)
                    out[(((size_t)(b * NH + h)) * HD + d) * TSEQ + t] = v;
                else
                    out[(((size_t)(b * NH + h)) * TSEQ + t) * HD + d] = v;
            }
}

// ---------------- output projection: out[M][1024] f32 = ctx * Wo^T + bo ----------------
__global__ __launch_bounds__(256) void gemm_out(const unsigned short* __restrict__ ctx,
                                                const unsigned short* __restrict__ Wob,
                                                const float* __restrict__ bo,
                                                float* __restrict__ out) {
    __shared__ __attribute__((aligned(16))) unsigned short As[128 * 32];
    __shared__ __attribute__((aligned(16))) unsigned short Bs[128 * 32];
    const int m0 = blockIdx.x * 128;
    const int n0 = blockIdx.y * 128;

    f32x4 acc[4][4];
    gemm_mainloop(ctx, Wob, m0, n0, DMODEL, As, Bs, acc);

    const int tid = threadIdx.x, lane = tid & 63, w = tid >> 6;
    const int wr = w >> 1, wc = w & 1;
#pragma unroll
    for (int i = 0; i < 4; i++)
#pragma unroll
        for (int j = 0; j < 4; j++)
#pragma unroll
            for (int r = 0; r < 4; r++) {
                int row = m0 + wr * 64 + i * 16 + (lane >> 4) * 4 + r;
                int col = n0 + wc * 64 + j * 16 + (lane & 15);
                out[(size_t)row * DMODEL + col] = acc[i][j][r] + bo[col];
            }
}

// ---------------- flash attention (causal), Q-tile 128, KV-tile 64, 4 waves ----------------
// Q,K: [B,H,T,hd] bf16 ; Vt: [B,H,hd,T] bf16 ; ctx out: [B,T,H,hd] bf16
__global__ __launch_bounds__(256) void attn(const unsigned short* __restrict__ Qg,
                                            const unsigned short* __restrict__ Kg,
                                            const unsigned short* __restrict__ Vg,
                                            unsigned short* __restrict__ ctx) {
    __shared__ __attribute__((aligned(16))) unsigned short Ks[64][72];
    __shared__ __attribute__((aligned(16))) unsigned short Vs[64][72];
    __shared__ __attribute__((aligned(16))) float Sl[128][68];  // S f32; P bf16 overlaid in-place
    __shared__ float mrow[128], lrow_[128], resc[128];
    unsigned short* Pl = (unsigned short*)&Sl[0][0];  // row r at ushort offset r*136

    const int tid = threadIdx.x, lane = tid & 63, w = tid >> 6;
    const int wq = w * 32;
    const int bh = blockIdx.x;            // b*16+h
    const int q0 = blockIdx.y * 128;
    const unsigned short* Qh = Qg + (size_t)bh * TSEQ * HD;
    const unsigned short* Kh = Kg + (size_t)bh * TSEQ * HD;
    const unsigned short* Vh = Vg + (size_t)bh * HD * TSEQ;

    // stage Q tile [128][64] into the S/P buffer (stride 136 ushorts)
    for (int c = tid; c < 1024; c += 256) {
        int r = c >> 3, off = (c & 7) * 8;
        *(short8*)&Pl[r * 136 + off] = *(const short8*)(Qh + (size_t)(q0 + r) * HD + off);
    }
    __syncthreads();
    short8 qf[2][2];
#pragma unroll
    for (int rb = 0; rb < 2; rb++)
#pragma unroll
        for (int ks = 0; ks < 2; ks++)
            qf[rb][ks] = *(const short8*)&Pl[(wq + rb * 16 + (lane & 15)) * 136 + ks * 32 + (lane >> 4) * 8];
    if (tid < 128) { mrow[tid] = -INFINITY; lrow_[tid] = 0.f; }
    f32x4 zero = {0.f, 0.f, 0.f, 0.f};
    f32x4 o[2][4];
#pragma unroll
    for (int rb = 0; rb < 2; rb++)
#pragma unroll
        for (int db = 0; db < 4; db++) o[rb][db] = zero;
    __syncthreads();  // everyone has read Q before S/P buffer is reused

    const int nkv = q0 / 64 + 2;
    for (int kt = 0; kt < nkv; kt++) {
        const int kv0 = kt * 64;
        // stage K tile [64][64] and Vt tile [64(d)][64(t)]
        for (int c = tid; c < 512; c += 256) {
            int r = c >> 3, off = (c & 7) * 8;
            *(short8*)&Ks[r][off] = *(const short8*)(Kh + (size_t)(kv0 + r) * HD + off);
            *(short8*)&Vs[r][off] = *(const short8*)(Vh + (size_t)r * TSEQ + kv0 + off);
        }
        __syncthreads();

        // S = Q*K^T
        f32x4 s[2][4];
#pragma unroll
        for (int rb = 0; rb < 2; rb++)
#pragma unroll
            for (int cb = 0; cb < 4; cb++) s[rb][cb] = zero;
#pragma unroll
        for (int ks = 0; ks < 2; ks++) {
            short8 bfrag[4];
#pragma unroll
            for (int cb = 0; cb < 4; cb++)
                bfrag[cb] = *(const short8*)&Ks[cb * 16 + (lane & 15)][ks * 32 + (lane >> 4) * 8];
#pragma unroll
            for (int rb = 0; rb < 2; rb++)
#pragma unroll
                for (int cb = 0; cb < 4; cb++)
                    s[rb][cb] = __builtin_amdgcn_mfma_f32_16x16x32_bf16(qf[rb][ks], bfrag[cb], s[rb][cb], 0, 0, 0);
        }
        // scale + causal mask + write S to LDS
#pragma unroll
        for (int rb = 0; rb < 2; rb++)
#pragma unroll
            for (int cb = 0; cb < 4; cb++)
#pragma unroll
                for (int r = 0; r < 4; r++) {
                    int ql = wq + rb * 16 + (lane >> 4) * 4 + r;
                    int kvl = cb * 16 + (lane & 15);
                    float v = s[rb][cb][r] * 0.125f;
                    if (kv0 + kvl > q0 + ql) v = -INFINITY;
                    Sl[ql][kvl] = v;
                }
        __syncthreads();

        // online softmax: one thread per row
        if (tid < 128) {
            int r = tid;
            float mold = mrow[r];
            float mx = mold;
            for (int j = 0; j < 64; j++) mx = fmaxf(mx, Sl[r][j]);
            float rs = __expf(mold - mx);
            float sum = 0.f;
            for (int j = 0; j < 64; j++) {
                float p = __expf(Sl[r][j] - mx);
                Pl[r * 136 + j] = f2bf(p);  // in-place overlay: write byte 2j after reading byte 4j
                sum += p;
            }
            mrow[r] = mx;
            lrow_[r] = lrow_[r] * rs + sum;
            resc[r] = rs;
        }
        __syncthreads();

        // rescale ctx accumulators, then ctx += P*V
        float rsc[2][4];
#pragma unroll
        for (int rb = 0; rb < 2; rb++)
#pragma unroll
            for (int r = 0; r < 4; r++)
                rsc[rb][r] = resc[wq + rb * 16 + (lane >> 4) * 4 + r];
#pragma unroll
        for (int rb = 0; rb < 2; rb++)
#pragma unroll
            for (int db = 0; db < 4; db++)
#pragma unroll
                for (int r = 0; r < 4; r++) o[rb][db][r] *= rsc[rb][r];
#pragma unroll
        for (int ks = 0; ks < 2; ks++) {
            short8 pa[2], vb[4];
#pragma unroll
            for (int rb = 0; rb < 2; rb++)
                pa[rb] = *(const short8*)&Pl[(wq + rb * 16 + (lane & 15)) * 136 + ks * 32 + (lane >> 4) * 8];
#pragma unroll
            for (int db = 0; db < 4; db++)
                vb[db] = *(const short8*)&Vs[db * 16 + (lane & 15)][ks * 32 + (lane >> 4) * 8];
#pragma unroll
            for (int rb = 0; rb < 2; rb++)
#pragma unroll
                for (int db = 0; db < 4; db++)
                    o[rb][db] = __builtin_amdgcn_mfma_f32_16x16x32_bf16(pa[rb], vb[db], o[rb][db], 0, 0, 0);
        }
        __syncthreads();
    }

    // epilogue: ctx = o / l, to [B,T,H,hd]
    const int b = bh >> 4, h = bh & 15;
#pragma unroll
    for (int rb = 0; rb < 2; rb++) {
        float linv[4];
#pragma unroll
        for (int r = 0; r < 4; r++)
            linv[r] = 1.f / lrow_[wq + rb * 16 + (lane >> 4) * 4 + r];
#pragma unroll
        for (int db = 0; db < 4; db++)
#pragma unroll
            for (int r = 0; r < 4; r++) {
                int ql = wq + rb * 16 + (lane >> 4) * 4 + r;
                int d = db * 16 + (lane & 15);
                ctx[(((size_t)(b * TSEQ + q0 + ql)) * NH + h) * HD + d] = f2bf(o[rb][db][r] * linv[r]);
            }
    }
}

extern "C" void kernel_launch(void* const* d_in, const int* in_sizes, int n_in,
                              void* d_out, int out_size, void* d_ws, size_t ws_size,
                              hipStream_t stream) {
    const float* x  = (const float*)d_in[0];
    const float* Wq = (const float*)d_in[1];
    const float* Wk = (const float*)d_in[2];
    const float* Wv = (const float*)d_in[3];
    const float* Wo = (const float*)d_in[4];
    const float* bo = (const float*)d_in[5];
    float* out = (float*)d_out;

    char* ws = (char*)d_ws;
    unsigned short* xb   = (unsigned short*)(ws);             // 16,777,216 B
    unsigned short* Wqb  = (unsigned short*)(ws + 16777216);  //  2,097,152 B
    unsigned short* Wkb  = (unsigned short*)(ws + 18874368);
    unsigned short* Wvb  = (unsigned short*)(ws + 20971520);
    unsigned short* Wob  = (unsigned short*)(ws + 23068672);
    unsigned short* Qb   = (unsigned short*)(ws + 25165824);  // [B,H,T,hd] bf16
    unsigned short* Kb   = (unsigned short*)(ws + 41943040);  // [B,H,T,hd]
    unsigned short* Vtb  = (unsigned short*)(ws + 58720256);  // [B,H,hd,T]
    unsigned short* ctxb = (unsigned short*)(ws + 75497472);  // [B,T,H,hd]

    cast_f32_bf16<<<8192, 256, 0, stream>>>(x, xb, 2097152);
    cast_f32_bf16<<<1024, 256, 0, stream>>>(Wq, Wqb, 262144);
    cast_f32_bf16<<<1024, 256, 0, stream>>>(Wk, Wkb, 262144);
    cast_f32_bf16<<<1024, 256, 0, stream>>>(Wv, Wvb, 262144);
    cast_f32_bf16<<<1024, 256, 0, stream>>>(Wo, Wob, 262144);

    gemm_qkv<<<dim3(64, 8, 3), 256, 0, stream>>>(xb, Wqb, Wkb, Wvb, Qb, Kb, Vtb);
    attn<<<dim3(64, 16), 256, 0, stream>>>(Qb, Kb, Vtb, ctxb);
    gemm_out<<<dim3(64, 8), 256, 0, stream>>>(ctxb, Wob, bo, out);
}

// Round 2
// 257.317 us; speedup vs baseline: 1.1951x; 1.1951x over previous
//
#include <hip/hip_runtime.h>

#define NH 16
#define HD 64
#define TSEQ 2048
#define DMODEL 1024

typedef __attribute__((ext_vector_type(8))) short short8;
typedef __attribute__((ext_vector_type(4))) float f32x4;

static __device__ __forceinline__ unsigned short f2bf(float f) {
    unsigned u = __builtin_bit_cast(unsigned, f);
    u += 0x7FFF + ((u >> 16) & 1);
    return (unsigned short)(u >> 16);
}

// ---------------- cast f32 -> bf16 (vectorized, n multiple of 4) ----------------
__global__ __launch_bounds__(256) void cast_f32_bf16(const float* __restrict__ src,
                                                     unsigned short* __restrict__ dst, int n4) {
    int i = blockIdx.x * 256 + threadIdx.x;
    if (i >= n4) return;
    float4 v = reinterpret_cast<const float4*>(src)[i];
    ushort4 o;
    o.x = f2bf(v.x); o.y = f2bf(v.y); o.z = f2bf(v.z); o.w = f2bf(v.w);
    reinterpret_cast<ushort4*>(dst)[i] = o;
}

// ---------------- m97-style GEMM mainloop: C[128x128] = A[M][K] * Bt[N][K]^T ----------------
static __device__ __forceinline__ void gemm_mainloop(const unsigned short* __restrict__ A,
                                                     const unsigned short* __restrict__ Bt,
                                                     int m0, int n0, int K,
                                                     unsigned short* As, unsigned short* Bs,
                                                     f32x4 acc[4][4]) {
    const int tid = threadIdx.x;
    const int lane = tid & 63;
    const int w = tid >> 6;
    const int wr = w >> 1, wc = w & 1;
    const int lrow = lane >> 2;          // 0..15
    const int lcol = (lane & 3) * 8;     // 0,8,16,24  (ushort units)

    f32x4 zero = {0.f, 0.f, 0.f, 0.f};
#pragma unroll
    for (int i = 0; i < 4; i++)
#pragma unroll
        for (int j = 0; j < 4; j++) acc[i][j] = zero;

    for (int k0 = 0; k0 < K; k0 += 32) {
        __syncthreads();
#pragma unroll
        for (int c = w; c < 8; c += 4) {
            int row = c * 16 + lrow;
            __builtin_amdgcn_global_load_lds(
                (const __attribute__((address_space(1))) void*)(A + (size_t)(m0 + row) * K + k0 + lcol),
                (__attribute__((address_space(3))) void*)(As + c * 512), 16, 0, 0);
            __builtin_amdgcn_global_load_lds(
                (const __attribute__((address_space(1))) void*)(Bt + (size_t)(n0 + row) * K + k0 + lcol),
                (__attribute__((address_space(3))) void*)(Bs + c * 512), 16, 0, 0);
        }
        __syncthreads();

        const int ko = (lane >> 4) * 8;
        short8 a[4], b[4];
#pragma unroll
        for (int i = 0; i < 4; i++)
            a[i] = *(const short8*)(As + (wr * 64 + i * 16 + (lane & 15)) * 32 + ko);
#pragma unroll
        for (int j = 0; j < 4; j++)
            b[j] = *(const short8*)(Bs + (wc * 64 + j * 16 + (lane & 15)) * 32 + ko);
#pragma unroll
        for (int i = 0; i < 4; i++)
#pragma unroll
            for (int j = 0; j < 4; j++)
                acc[i][j] = __builtin_amdgcn_mfma_f32_16x16x32_bf16(a[i], b[j], acc[i][j], 0, 0, 0);
    }
}

// ---------------- QKV projection ----------------
__global__ __launch_bounds__(256) void gemm_qkv(const unsigned short* __restrict__ xb,
                                                const unsigned short* __restrict__ Wqb,
                                                const unsigned short* __restrict__ Wkb,
                                                const unsigned short* __restrict__ Wvb,
                                                unsigned short* __restrict__ Q,
                                                unsigned short* __restrict__ K,
                                                unsigned short* __restrict__ Vt) {
    __shared__ __attribute__((aligned(16))) unsigned short As[128 * 32];
    __shared__ __attribute__((aligned(16))) unsigned short Bs[128 * 32];
    const int m0 = blockIdx.x * 128;
    const int n0 = blockIdx.y * 128;
    const int z = blockIdx.z;
    const unsigned short* Bt = (z == 0) ? Wqb : ((z == 1) ? Wkb : Wvb);
    unsigned short* out = (z == 0) ? Q : ((z == 1) ? K : Vt);

    f32x4 acc[4][4];
    gemm_mainloop(xb, Bt, m0, n0, DMODEL, As, Bs, acc);

    const int tid = threadIdx.x, lane = tid & 63, w = tid >> 6;
    const int wr = w >> 1, wc = w & 1;
#pragma unroll
    for (int i = 0; i < 4; i++)
#pragma unroll
        for (int j = 0; j < 4; j++)
#pragma unroll
            for (int r = 0; r < 4; r++) {
                int row = m0 + wr * 64 + i * 16 + (lane >> 4) * 4 + r;  // b*2048 + t
                int col = n0 + wc * 64 + j * 16 + (lane & 15);          // h*64 + d
                int b = row >> 11, t = row & 2047;
                int h = col >> 6, d = col & 63;
                unsigned short v = f2bf(acc[i][j][r]);
                if (z == 2)
                    out[(((size_t)(b * NH + h)) * HD + d) * TSEQ + t] = v;
                else
                    out[(((size_t)(b * NH + h)) * TSEQ + t) * HD + d] = v;
            }
}

// ---------------- output projection ----------------
__global__ __launch_bounds__(256) void gemm_out(const unsigned short* __restrict__ ctx,
                                                const unsigned short* __restrict__ Wob,
                                                const float* __restrict__ bo,
                                                float* __restrict__ out) {
    __shared__ __attribute__((aligned(16))) unsigned short As[128 * 32];
    __shared__ __attribute__((aligned(16))) unsigned short Bs[128 * 32];
    const int m0 = blockIdx.x * 128;
    const int n0 = blockIdx.y * 128;

    f32x4 acc[4][4];
    gemm_mainloop(ctx, Wob, m0, n0, DMODEL, As, Bs, acc);

    const int tid = threadIdx.x, lane = tid & 63, w = tid >> 6;
    const int wr = w >> 1, wc = w & 1;
#pragma unroll
    for (int i = 0; i < 4; i++)
#pragma unroll
        for (int j = 0; j < 4; j++)
#pragma unroll
            for (int r = 0; r < 4; r++) {
                int row = m0 + wr * 64 + i * 16 + (lane >> 4) * 4 + r;
                int col = n0 + wc * 64 + j * 16 + (lane & 15);
                out[(size_t)row * DMODEL + col] = acc[i][j][r] + bo[col];
            }
}

// ---------------- flash attention (causal), Q-tile 128, KV-tile 64, 4 waves ----------------
// Q,K: [B,H,T,hd] bf16 ; Vt: [B,H,hd,T] bf16 ; ctx out: [B,T,H,hd] bf16
// Wave-parallel in-register online softmax; P transposed through per-wave-private LDS slice.
__global__ __launch_bounds__(256) void attn(const unsigned short* __restrict__ Qg,
                                            const unsigned short* __restrict__ Kg,
                                            const unsigned short* __restrict__ Vg,
                                            unsigned short* __restrict__ ctx) {
    __shared__ __attribute__((aligned(16))) unsigned short Ks[64][72];
    __shared__ __attribute__((aligned(16))) unsigned short Vs[64][72];
    __shared__ __attribute__((aligned(16))) unsigned short Pl[128][72];

    const int tid = threadIdx.x, lane = tid & 63, w = tid >> 6;
    const int wq = w * 32;
    const int lg = lane >> 4;        // 16-lane group id 0..3
    const int ll = lane & 15;
    const int bh = blockIdx.x;       // b*16+h
    const int q0 = (gridDim.y - 1 - blockIdx.y) * 128;   // heavy tiles first (LPT)
    const unsigned short* Qh = Qg + (size_t)bh * TSEQ * HD;
    const unsigned short* Kh = Kg + (size_t)bh * TSEQ * HD;
    const unsigned short* Vh = Vg + (size_t)bh * HD * TSEQ;

    // Q fragments straight from global (one-time, L2-friendly)
    short8 qf[2][2];
#pragma unroll
    for (int rb = 0; rb < 2; rb++)
#pragma unroll
        for (int ks = 0; ks < 2; ks++)
            qf[rb][ks] = *(const short8*)(Qh + (size_t)(q0 + wq + rb * 16 + ll) * HD + ks * 32 + lg * 8);

    float mrun[2][4], lrun[2][4];
#pragma unroll
    for (int rb = 0; rb < 2; rb++)
#pragma unroll
        for (int r = 0; r < 4; r++) { mrun[rb][r] = -1e30f; lrun[rb][r] = 0.f; }
    f32x4 zero = {0.f, 0.f, 0.f, 0.f};
    f32x4 o[2][4];
#pragma unroll
    for (int rb = 0; rb < 2; rb++)
#pragma unroll
        for (int db = 0; db < 4; db++) o[rb][db] = zero;

    const int nkv = q0 / 64 + 2;
    for (int kt = 0; kt < nkv; kt++) {
        const int kv0 = kt * 64;
        // stage K tile [64][64] and Vt tile [64(d)][64(t)]
        for (int c = tid; c < 512; c += 256) {
            int r = c >> 3, off = (c & 7) * 8;
            *(short8*)&Ks[r][off] = *(const short8*)(Kh + (size_t)(kv0 + r) * HD + off);
            *(short8*)&Vs[r][off] = *(const short8*)(Vh + (size_t)r * TSEQ + kv0 + off);
        }
        __syncthreads();

        // S = Q*K^T  (C/D layout: row = 4*lg + r within 16-block, col = ll)
        f32x4 s[2][4];
#pragma unroll
        for (int rb = 0; rb < 2; rb++)
#pragma unroll
            for (int cb = 0; cb < 4; cb++) s[rb][cb] = zero;
#pragma unroll
        for (int ks = 0; ks < 2; ks++) {
            short8 bfrag[4];
#pragma unroll
            for (int cb = 0; cb < 4; cb++)
                bfrag[cb] = *(const short8*)&Ks[cb * 16 + ll][ks * 32 + lg * 8];
#pragma unroll
            for (int rb = 0; rb < 2; rb++)
#pragma unroll
                for (int cb = 0; cb < 4; cb++)
                    s[rb][cb] = __builtin_amdgcn_mfma_f32_16x16x32_bf16(qf[rb][ks], bfrag[cb], s[rb][cb], 0, 0, 0);
        }

        // scale + causal mask in-register
        const bool domask = (kv0 + 63 > q0);
#pragma unroll
        for (int rb = 0; rb < 2; rb++)
#pragma unroll
            for (int cb = 0; cb < 4; cb++)
#pragma unroll
                for (int r = 0; r < 4; r++) {
                    float v = s[rb][cb][r] * 0.125f;
                    if (domask) {
                        int ql = wq + rb * 16 + lg * 4 + r;
                        int kvl = cb * 16 + ll;
                        if (kv0 + kvl > q0 + ql) v = -1e30f;
                    }
                    s[rb][cb][r] = v;
                }

        // wave-parallel online softmax: each row's 64 vals live in 4 regs x 16 lanes
#pragma unroll
        for (int rb = 0; rb < 2; rb++)
#pragma unroll
            for (int r = 0; r < 4; r++) {
                float mx = fmaxf(fmaxf(s[rb][0][r], s[rb][1][r]), fmaxf(s[rb][2][r], s[rb][3][r]));
                mx = fmaxf(mx, __shfl_xor(mx, 1));
                mx = fmaxf(mx, __shfl_xor(mx, 2));
                mx = fmaxf(mx, __shfl_xor(mx, 4));
                mx = fmaxf(mx, __shfl_xor(mx, 8));
                float mold = mrun[rb][r];
                float mn = fmaxf(mold, mx);
                float rs = __expf(mold - mn);
                mrun[rb][r] = mn;
                float sum = 0.f;
#pragma unroll
                for (int cb = 0; cb < 4; cb++) {
                    float p = __expf(s[rb][cb][r] - mn);
                    sum += p;
                    Pl[wq + rb * 16 + lg * 4 + r][cb * 16 + ll] = f2bf(p);
                }
                sum += __shfl_xor(sum, 1);
                sum += __shfl_xor(sum, 2);
                sum += __shfl_xor(sum, 4);
                sum += __shfl_xor(sum, 8);
                lrun[rb][r] = lrun[rb][r] * rs + sum;
#pragma unroll
                for (int db = 0; db < 4; db++) o[rb][db][r] *= rs;
            }
        __syncthreads();  // P write -> P read (also covers K/V reuse below)

        // ctx += P*V   (P slice [wq, wq+32) is per-wave private)
#pragma unroll
        for (int ks = 0; ks < 2; ks++) {
            short8 pa[2], vb[4];
#pragma unroll
            for (int rb = 0; rb < 2; rb++)
                pa[rb] = *(const short8*)&Pl[wq + rb * 16 + ll][ks * 32 + lg * 8];
#pragma unroll
            for (int db = 0; db < 4; db++)
                vb[db] = *(const short8*)&Vs[db * 16 + ll][ks * 32 + lg * 8];
#pragma unroll
            for (int rb = 0; rb < 2; rb++)
#pragma unroll
                for (int db = 0; db < 4; db++)
                    o[rb][db] = __builtin_amdgcn_mfma_f32_16x16x32_bf16(pa[rb], vb[db], o[rb][db], 0, 0, 0);
        }
        __syncthreads();  // all waves done with Ks/Vs before next staging
    }

    // epilogue: ctx = o / l, to [B,T,H,hd]
    const int b = bh >> 4, h = bh & 15;
#pragma unroll
    for (int rb = 0; rb < 2; rb++) {
        float linv[4];
#pragma unroll
        for (int r = 0; r < 4; r++) linv[r] = 1.f / lrun[rb][r];
#pragma unroll
        for (int db = 0; db < 4; db++)
#pragma unroll
            for (int r = 0; r < 4; r++) {
                int ql = wq + rb * 16 + lg * 4 + r;
                int d = db * 16 + ll;
                ctx[(((size_t)(b * TSEQ + q0 + ql)) * NH + h) * HD + d] = f2bf(o[rb][db][r] * linv[r]);
            }
    }
}

extern "C" void kernel_launch(void* const* d_in, const int* in_sizes, int n_in,
                              void* d_out, int out_size, void* d_ws, size_t ws_size,
                              hipStream_t stream) {
    const float* x  = (const float*)d_in[0];
    const float* Wq = (const float*)d_in[1];
    const float* Wk = (const float*)d_in[2];
    const float* Wv = (const float*)d_in[3];
    const float* Wo = (const float*)d_in[4];
    const float* bo = (const float*)d_in[5];
    float* out = (float*)d_out;

    char* ws = (char*)d_ws;
    unsigned short* xb   = (unsigned short*)(ws);             // 16,777,216 B
    unsigned short* Wqb  = (unsigned short*)(ws + 16777216);
    unsigned short* Wkb  = (unsigned short*)(ws + 18874368);
    unsigned short* Wvb  = (unsigned short*)(ws + 20971520);
    unsigned short* Wob  = (unsigned short*)(ws + 23068672);
    unsigned short* Qb   = (unsigned short*)(ws + 25165824);  // [B,H,T,hd] bf16
    unsigned short* Kb   = (unsigned short*)(ws + 41943040);  // [B,H,T,hd]
    unsigned short* Vtb  = (unsigned short*)(ws + 58720256);  // [B,H,hd,T]
    unsigned short* ctxb = (unsigned short*)(ws + 75497472);  // [B,T,H,hd]

    cast_f32_bf16<<<8192, 256, 0, stream>>>(x, xb, 2097152);
    cast_f32_bf16<<<1024, 256, 0, stream>>>(Wq, Wqb, 262144);
    cast_f32_bf16<<<1024, 256, 0, stream>>>(Wk, Wkb, 262144);
    cast_f32_bf16<<<1024, 256, 0, stream>>>(Wv, Wvb, 262144);
    cast_f32_bf16<<<1024, 256, 0, stream>>>(Wo, Wob, 262144);

    gemm_qkv<<<dim3(64, 8, 3), 256, 0, stream>>>(xb, Wqb, Wkb, Wvb, Qb, Kb, Vtb);
    attn<<<dim3(64, 16), 256, 0, stream>>>(Qb, Kb, Vtb, ctxb);
    gemm_out<<<dim3(64, 8), 256, 0, stream>>>(ctxb, Wob, bo, out);
}

// Round 3
// 244.687 us; speedup vs baseline: 1.2568x; 1.0516x over previous
//
#include <hip/hip_runtime.h>

#define NH 16
#define HD 64
#define TSEQ 2048
#define DMODEL 1024

typedef __attribute__((ext_vector_type(8))) short short8;
typedef __attribute__((ext_vector_type(4))) float f32x4;

static __device__ __forceinline__ unsigned short f2bf(float f) {
    unsigned u = __builtin_bit_cast(unsigned, f);
    u += 0x7FFF + ((u >> 16) & 1);
    return (unsigned short)(u >> 16);
}

// ---------------- cast f32 -> bf16 (vectorized, n multiple of 4) ----------------
__global__ __launch_bounds__(256) void cast_f32_bf16(const float* __restrict__ src,
                                                     unsigned short* __restrict__ dst, int n4) {
    int i = blockIdx.x * 256 + threadIdx.x;
    if (i >= n4) return;
    float4 v = reinterpret_cast<const float4*>(src)[i];
    ushort4 o;
    o.x = f2bf(v.x); o.y = f2bf(v.y); o.z = f2bf(v.z); o.w = f2bf(v.w);
    reinterpret_cast<ushort4*>(dst)[i] = o;
}

// ---------------- m97-style GEMM mainloop: C[128x128] = A[M][K] * Bt[N][K]^T ----------------
static __device__ __forceinline__ void gemm_mainloop(const unsigned short* __restrict__ A,
                                                     const unsigned short* __restrict__ Bt,
                                                     int m0, int n0, int K,
                                                     unsigned short* As, unsigned short* Bs,
                                                     f32x4 acc[4][4]) {
    const int tid = threadIdx.x;
    const int lane = tid & 63;
    const int w = tid >> 6;
    const int wr = w >> 1, wc = w & 1;
    const int lrow = lane >> 2;          // 0..15
    const int lcol = (lane & 3) * 8;     // 0,8,16,24  (ushort units)

    f32x4 zero = {0.f, 0.f, 0.f, 0.f};
#pragma unroll
    for (int i = 0; i < 4; i++)
#pragma unroll
        for (int j = 0; j < 4; j++) acc[i][j] = zero;

    for (int k0 = 0; k0 < K; k0 += 32) {
        __syncthreads();
#pragma unroll
        for (int c = w; c < 8; c += 4) {
            int row = c * 16 + lrow;
            __builtin_amdgcn_global_load_lds(
                (const __attribute__((address_space(1))) void*)(A + (size_t)(m0 + row) * K + k0 + lcol),
                (__attribute__((address_space(3))) void*)(As + c * 512), 16, 0, 0);
            __builtin_amdgcn_global_load_lds(
                (const __attribute__((address_space(1))) void*)(Bt + (size_t)(n0 + row) * K + k0 + lcol),
                (__attribute__((address_space(3))) void*)(Bs + c * 512), 16, 0, 0);
        }
        __syncthreads();

        const int ko = (lane >> 4) * 8;
        short8 a[4], b[4];
#pragma unroll
        for (int i = 0; i < 4; i++)
            a[i] = *(const short8*)(As + (wr * 64 + i * 16 + (lane & 15)) * 32 + ko);
#pragma unroll
        for (int j = 0; j < 4; j++)
            b[j] = *(const short8*)(Bs + (wc * 64 + j * 16 + (lane & 15)) * 32 + ko);
#pragma unroll
        for (int i = 0; i < 4; i++)
#pragma unroll
            for (int j = 0; j < 4; j++)
                acc[i][j] = __builtin_amdgcn_mfma_f32_16x16x32_bf16(a[i], b[j], acc[i][j], 0, 0, 0);
    }
}

// ---------------- QKV projection ----------------
// Q is pre-scaled by 0.125 * log2(e) so attention can use exp2 with no per-element scaling.
#define QSCALE 0.180336880f
__global__ __launch_bounds__(256) void gemm_qkv(const unsigned short* __restrict__ xb,
                                                const unsigned short* __restrict__ Wqb,
                                                const unsigned short* __restrict__ Wkb,
                                                const unsigned short* __restrict__ Wvb,
                                                unsigned short* __restrict__ Q,
                                                unsigned short* __restrict__ K,
                                                unsigned short* __restrict__ Vt) {
    __shared__ __attribute__((aligned(16))) unsigned short As[128 * 32];
    __shared__ __attribute__((aligned(16))) unsigned short Bs[128 * 32];
    const int m0 = blockIdx.x * 128;
    const int n0 = blockIdx.y * 128;
    const int z = blockIdx.z;
    const unsigned short* Bt = (z == 0) ? Wqb : ((z == 1) ? Wkb : Wvb);
    unsigned short* out = (z == 0) ? Q : ((z == 1) ? K : Vt);

    f32x4 acc[4][4];
    gemm_mainloop(xb, Bt, m0, n0, DMODEL, As, Bs, acc);

    const int tid = threadIdx.x, lane = tid & 63, w = tid >> 6;
    const int wr = w >> 1, wc = w & 1;
    const float sc = (z == 0) ? QSCALE : 1.0f;
#pragma unroll
    for (int i = 0; i < 4; i++)
#pragma unroll
        for (int j = 0; j < 4; j++)
#pragma unroll
            for (int r = 0; r < 4; r++) {
                int row = m0 + wr * 64 + i * 16 + (lane >> 4) * 4 + r;  // b*2048 + t
                int col = n0 + wc * 64 + j * 16 + (lane & 15);          // h*64 + d
                int b = row >> 11, t = row & 2047;
                int h = col >> 6, d = col & 63;
                unsigned short v = f2bf(acc[i][j][r] * sc);
                if (z == 2)
                    out[(((size_t)(b * NH + h)) * HD + d) * TSEQ + t] = v;
                else
                    out[(((size_t)(b * NH + h)) * TSEQ + t) * HD + d] = v;
            }
}

// ---------------- output projection ----------------
__global__ __launch_bounds__(256) void gemm_out(const unsigned short* __restrict__ ctx,
                                                const unsigned short* __restrict__ Wob,
                                                const float* __restrict__ bo,
                                                float* __restrict__ out) {
    __shared__ __attribute__((aligned(16))) unsigned short As[128 * 32];
    __shared__ __attribute__((aligned(16))) unsigned short Bs[128 * 32];
    const int m0 = blockIdx.x * 128;
    const int n0 = blockIdx.y * 128;

    f32x4 acc[4][4];
    gemm_mainloop(ctx, Wob, m0, n0, DMODEL, As, Bs, acc);

    const int tid = threadIdx.x, lane = tid & 63, w = tid >> 6;
    const int wr = w >> 1, wc = w & 1;
#pragma unroll
    for (int i = 0; i < 4; i++)
#pragma unroll
        for (int j = 0; j < 4; j++)
#pragma unroll
            for (int r = 0; r < 4; r++) {
                int row = m0 + wr * 64 + i * 16 + (lane >> 4) * 4 + r;
                int col = n0 + wc * 64 + j * 16 + (lane & 15);
                out[(size_t)row * DMODEL + col] = acc[i][j][r] + bo[col];
            }
}

// ---------------- flash attention (causal), Q-tile 128, KV-tile 64, 4 waves ----------------
// Q (pre-scaled), K: [B,H,T,hd] bf16 ; Vt: [B,H,hd,T] bf16 ; ctx out: [B,T,H,hd] bf16
// T14 async staging, T13 defer-max, exp2 softmax, wave-private P slice (no mid barrier).
__global__ __launch_bounds__(256) void attn(const unsigned short* __restrict__ Qg,
                                            const unsigned short* __restrict__ Kg,
                                            const unsigned short* __restrict__ Vg,
                                            unsigned short* __restrict__ ctx) {
    __shared__ __attribute__((aligned(16))) unsigned short Ks[64][72];
    __shared__ __attribute__((aligned(16))) unsigned short Vs[64][72];
    __shared__ __attribute__((aligned(16))) unsigned short Pl[128][72];

    const int tid = threadIdx.x, lane = tid & 63, w = tid >> 6;
    const int wq = w * 32;
    const int lg = lane >> 4;        // 16-lane group id 0..3
    const int ll = lane & 15;
    const int bh = blockIdx.x;       // b*16+h
    const int q0 = (gridDim.y - 1 - blockIdx.y) * 128;   // heavy tiles first (LPT)
    const unsigned short* Qh = Qg + (size_t)bh * TSEQ * HD;
    const unsigned short* Kh = Kg + (size_t)bh * TSEQ * HD;
    const unsigned short* Vh = Vg + (size_t)bh * HD * TSEQ;

    // Q fragments straight from global (one-time, L2-friendly)
    short8 qf[2][2];
#pragma unroll
    for (int rb = 0; rb < 2; rb++)
#pragma unroll
        for (int ks = 0; ks < 2; ks++)
            qf[rb][ks] = *(const short8*)(Qh + (size_t)(q0 + wq + rb * 16 + ll) * HD + ks * 32 + lg * 8);

    float mrun[2][4], lrun[2][4];
#pragma unroll
    for (int rb = 0; rb < 2; rb++)
#pragma unroll
        for (int r = 0; r < 4; r++) { mrun[rb][r] = -1e30f; lrun[rb][r] = 0.f; }
    f32x4 zero = {0.f, 0.f, 0.f, 0.f};
    f32x4 o[2][4];
#pragma unroll
    for (int rb = 0; rb < 2; rb++)
#pragma unroll
        for (int db = 0; db < 4; db++) o[rb][db] = zero;

    // async staging: thread covers rows sr and sr+32, 16B each
    const int sr = tid >> 3;          // 0..31
    const int sc = (tid & 7) * 8;     // ushort offset 0..56
    short8 kreg0, kreg1, vreg0, vreg1;
    {
        kreg0 = *(const short8*)(Kh + (size_t)(sr) * HD + sc);
        kreg1 = *(const short8*)(Kh + (size_t)(sr + 32) * HD + sc);
        vreg0 = *(const short8*)(Vh + (size_t)sr * TSEQ + sc);
        vreg1 = *(const short8*)(Vh + (size_t)(sr + 32) * TSEQ + sc);
    }

    const int nkv = q0 / 64 + 2;
    for (int kt = 0; kt < nkv; kt++) {
        const int kv0 = kt * 64;
        __syncthreads();   // previous tile's readers done with Ks/Vs
        *(short8*)&Ks[sr][sc] = kreg0;
        *(short8*)&Ks[sr + 32][sc] = kreg1;
        *(short8*)&Vs[sr][sc] = vreg0;
        *(short8*)&Vs[sr + 32][sc] = vreg1;
        if (kt + 1 < nkv) {           // issue next tile's loads; latency hides under compute
            const int nv0 = kv0 + 64;
            kreg0 = *(const short8*)(Kh + (size_t)(nv0 + sr) * HD + sc);
            kreg1 = *(const short8*)(Kh + (size_t)(nv0 + sr + 32) * HD + sc);
            vreg0 = *(const short8*)(Vh + (size_t)sr * TSEQ + nv0 + sc);
            vreg1 = *(const short8*)(Vh + (size_t)(sr + 32) * TSEQ + nv0 + sc);
        }
        __syncthreads();   // staged tile visible

        // S = Q*K^T  (C/D layout: row = 4*lg + r within 16-block, col = ll)
        f32x4 s[2][4];
#pragma unroll
        for (int rb = 0; rb < 2; rb++)
#pragma unroll
            for (int cb = 0; cb < 4; cb++) s[rb][cb] = zero;
#pragma unroll
        for (int ks = 0; ks < 2; ks++) {
            short8 bfrag[4];
#pragma unroll
            for (int cb = 0; cb < 4; cb++)
                bfrag[cb] = *(const short8*)&Ks[cb * 16 + ll][ks * 32 + lg * 8];
#pragma unroll
            for (int rb = 0; rb < 2; rb++)
#pragma unroll
                for (int cb = 0; cb < 4; cb++)
                    s[rb][cb] = __builtin_amdgcn_mfma_f32_16x16x32_bf16(qf[rb][ks], bfrag[cb], s[rb][cb], 0, 0, 0);
        }

        // causal mask (only near-diagonal tiles); S already in exp2 scale
        if (kv0 + 63 > q0) {
#pragma unroll
            for (int rb = 0; rb < 2; rb++)
#pragma unroll
                for (int cb = 0; cb < 4; cb++)
#pragma unroll
                    for (int r = 0; r < 4; r++) {
                        int ql = wq + rb * 16 + lg * 4 + r;
                        int kvl = cb * 16 + ll;
                        if (kv0 + kvl > q0 + ql) s[rb][cb][r] = -1e30f;
                    }
        }

        // row max for all 8 rows handled by this lane
        float mx8[2][4];
#pragma unroll
        for (int rb = 0; rb < 2; rb++)
#pragma unroll
            for (int r = 0; r < 4; r++) {
                float mx = fmaxf(fmaxf(s[rb][0][r], s[rb][1][r]), fmaxf(s[rb][2][r], s[rb][3][r]));
                mx = fmaxf(mx, __shfl_xor(mx, 1));
                mx = fmaxf(mx, __shfl_xor(mx, 2));
                mx = fmaxf(mx, __shfl_xor(mx, 4));
                mx = fmaxf(mx, __shfl_xor(mx, 8));
                mx8[rb][r] = mx;
            }
        // defer-max: rescale only when some row grew past THR=8 (exp2 scale -> P <= 256)
        float need = 0.f;
#pragma unroll
        for (int rb = 0; rb < 2; rb++)
#pragma unroll
            for (int r = 0; r < 4; r++) need = fmaxf(need, mx8[rb][r] - mrun[rb][r]);
        if (__any(need > 8.f)) {
#pragma unroll
            for (int rb = 0; rb < 2; rb++)
#pragma unroll
                for (int r = 0; r < 4; r++) {
                    float mold = mrun[rb][r];
                    float mn = fmaxf(mold, mx8[rb][r]);
                    float rs = __builtin_amdgcn_exp2f(mold - mn);
                    mrun[rb][r] = mn;
                    lrun[rb][r] *= rs;
#pragma unroll
                    for (int db = 0; db < 4; db++) o[rb][db][r] *= rs;
                }
        }
        // P = exp2(S - m), cheap round-to-nearest bf16, write to wave-private LDS slice
#pragma unroll
        for (int rb = 0; rb < 2; rb++)
#pragma unroll
            for (int r = 0; r < 4; r++) {
                float m = mrun[rb][r];
                float sum = 0.f;
#pragma unroll
                for (int cb = 0; cb < 4; cb++) {
                    float p = __builtin_amdgcn_exp2f(s[rb][cb][r] - m);
                    sum += p;
                    unsigned u = __builtin_bit_cast(unsigned, p);
                    Pl[wq + rb * 16 + lg * 4 + r][cb * 16 + ll] = (unsigned short)((u + 0x8000u) >> 16);
                }
                sum += __shfl_xor(sum, 1);
                sum += __shfl_xor(sum, 2);
                sum += __shfl_xor(sum, 4);
                sum += __shfl_xor(sum, 8);
                lrun[rb][r] += sum;
            }
        // wave-private P: no __syncthreads needed, just drain this wave's LDS ops
        asm volatile("s_waitcnt lgkmcnt(0)" ::: "memory");
        __builtin_amdgcn_sched_barrier(0);

        // ctx += P*V   (P slice [wq, wq+32) is per-wave private)
#pragma unroll
        for (int ks = 0; ks < 2; ks++) {
            short8 pa[2], vb[4];
#pragma unroll
            for (int rb = 0; rb < 2; rb++)
                pa[rb] = *(const short8*)&Pl[wq + rb * 16 + ll][ks * 32 + lg * 8];
#pragma unroll
            for (int db = 0; db < 4; db++)
                vb[db] = *(const short8*)&Vs[db * 16 + ll][ks * 32 + lg * 8];
#pragma unroll
            for (int rb = 0; rb < 2; rb++)
#pragma unroll
                for (int db = 0; db < 4; db++)
                    o[rb][db] = __builtin_amdgcn_mfma_f32_16x16x32_bf16(pa[rb], vb[db], o[rb][db], 0, 0, 0);
        }
    }

    // epilogue: ctx = o / l, to [B,T,H,hd]
    const int b = bh >> 4, h = bh & 15;
#pragma unroll
    for (int rb = 0; rb < 2; rb++) {
        float linv[4];
#pragma unroll
        for (int r = 0; r < 4; r++) linv[r] = 1.f / lrun[rb][r];
#pragma unroll
        for (int db = 0; db < 4; db++)
#pragma unroll
            for (int r = 0; r < 4; r++) {
                int ql = wq + rb * 16 + lg * 4 + r;
                int d = db * 16 + ll;
                ctx[(((size_t)(b * TSEQ + q0 + ql)) * NH + h) * HD + d] = f2bf(o[rb][db][r] * linv[r]);
            }
    }
}

extern "C" void kernel_launch(void* const* d_in, const int* in_sizes, int n_in,
                              void* d_out, int out_size, void* d_ws, size_t ws_size,
                              hipStream_t stream) {
    const float* x  = (const float*)d_in[0];
    const float* Wq = (const float*)d_in[1];
    const float* Wk = (const float*)d_in[2];
    const float* Wv = (const float*)d_in[3];
    const float* Wo = (const float*)d_in[4];
    const float* bo = (const float*)d_in[5];
    float* out = (float*)d_out;

    char* ws = (char*)d_ws;
    unsigned short* xb   = (unsigned short*)(ws);             // 16,777,216 B
    unsigned short* Wqb  = (unsigned short*)(ws + 16777216);
    unsigned short* Wkb  = (unsigned short*)(ws + 18874368);
    unsigned short* Wvb  = (unsigned short*)(ws + 20971520);
    unsigned short* Wob  = (unsigned short*)(ws + 23068672);
    unsigned short* Qb   = (unsigned short*)(ws + 25165824);  // [B,H,T,hd] bf16 (pre-scaled)
    unsigned short* Kb   = (unsigned short*)(ws + 41943040);  // [B,H,T,hd]
    unsigned short* Vtb  = (unsigned short*)(ws + 58720256);  // [B,H,hd,T]
    unsigned short* ctxb = (unsigned short*)(ws + 75497472);  // [B,T,H,hd]

    cast_f32_bf16<<<8192, 256, 0, stream>>>(x, xb, 2097152);
    cast_f32_bf16<<<1024, 256, 0, stream>>>(Wq, Wqb, 262144);
    cast_f32_bf16<<<1024, 256, 0, stream>>>(Wk, Wkb, 262144);
    cast_f32_bf16<<<1024, 256, 0, stream>>>(Wv, Wvb, 262144);
    cast_f32_bf16<<<1024, 256, 0, stream>>>(Wo, Wob, 262144);

    gemm_qkv<<<dim3(64, 8, 3), 256, 0, stream>>>(xb, Wqb, Wkb, Wvb, Qb, Kb, Vtb);
    attn<<<dim3(64, 16), 256, 0, stream>>>(Qb, Kb, Vtb, ctxb);
    gemm_out<<<dim3(64, 8), 256, 0, stream>>>(ctxb, Wob, bo, out);
}